// Round 3
// baseline (937.094 us; speedup 1.0000x reference)
//
#include <hip/hip_runtime.h>
#include <hip/hip_fp16.h>
#include <string.h>

#define PER  149796
#define NN   1048573          // 1 + 7*PER
#define HDIM 64
#define EDIM 32
#define NIOU 192

typedef _Float16 f16;
typedef _Float16 f16x8 __attribute__((ext_vector_type(8)));
typedef _Float16 f16x2 __attribute__((ext_vector_type(2)));
typedef float    f32x4 __attribute__((ext_vector_type(4)));

__device__ __forceinline__ float sigf(float x){ return 1.0f/(1.0f+__expf(-x)); }
__device__ __forceinline__ float tanh_f(float x){
  float ax = fabsf(x);
  float e  = __expf(-2.0f*ax);
  float t  = (1.0f - e)/(1.0f + e);
  return x < 0.0f ? -t : t;
}

// packed f16x2 global atomic add (fire-and-forget).
__device__ __forceinline__ void atomAddH2(f16x2* p, f16 a, f16 b){
#if defined(__HIP_DEVICE_COMPILE__)
  typedef _Float16 h2 __attribute__((ext_vector_type(2)));
  h2 v; v[0]=a; v[1]=b;
  (void)__builtin_amdgcn_global_atomic_fadd_v2f16(
      (__attribute__((address_space(1))) h2*)p, v);
#else
  (void)p; (void)a; (void)b;
#endif
}

// ================= tables + MFMA packs (fused) =================
// B-frag order for mfma_f32_16x16x32_f16 (verified R4): lane L: n=t*16+(L&15), k=s*32+(L>>4)*8+j
// K-extended packs: slice s=2 holds the W (input) matrix so the MFMA computes
// [h | x] @ [U ; W]^T in one accumulator chain.
__global__ __launch_bounds__(256) void tablepack_kernel(
    const float* __restrict__ emb, const float* __restrict__ Wiou,
    const float* __restrict__ Wf,
    const float* __restrict__ Uf, const float* __restrict__ Uiou,
    f16* __restrict__ emb16,
    f16* __restrict__ Bfp, f16* __restrict__ Biop)
{
  if (blockIdx.x < 1024){
    int v = blockIdx.x;
    int m = threadIdx.x;
    if (m < EDIM) emb16[(size_t)v*EDIM + m] = (f16)emb[(size_t)v*EDIM + m];
  } else {
    for (int i = threadIdx.x; i < 3*4*64*8; i += 256){
      int j = i & 7, L = (i>>3)&63, st = i>>9;
      int t = st & 3, s = st >> 2;
      int kk = (L>>4)*8 + j;
      int n = t*16 + (L&15);
      Bfp[i] = (s < 2) ? (f16)Uf[n*HDIM + s*32 + kk]
                       : (f16)Wf[n*EDIM + kk];
    }
    for (int i = threadIdx.x; i < 3*12*64*8; i += 256){
      int j = i & 7, L = (i>>3)&63, st = i>>9;
      int t = st % 12, s = st / 12;
      int kk = (L>>4)*8 + j;
      int n = t*16 + (L&15);
      Biop[i] = (s < 2) ? (f16)Uiou[n*HDIM + s*32 + kk]
                        : (f16)Wiou[n*EDIM + kk];
    }
  }
}

// ================= per-level kernel (push design, no CSR) =================
// 256 threads = 4 independent waves; each wave owns 16 nodes with a PRIVATE
// LDS slice -> no __syncthreads needed (DS ops are in-order per wave).
// A-tile is K=96: cols 0..63 = child-sum h, cols 64..95 = emb[token] (f16).
// mode: 0 = leaf (no accum read, atomic out)
//       1 = mid  (accum read, atomic out)
//       2 = level1 (accum read, plain contiguous out)
// zin: 1 -> zero own accIn rows after reading (they become accOut at the
//      next level), replacing a separate 38MB memset dispatch.
__global__ __launch_bounds__(256,7) void level_kernel(
    const int* __restrict__ tok, const int* __restrict__ parent,
    const f16* __restrict__ emb16,
    const float* __restrict__ biou, const float* __restrict__ bf,
    const f16* __restrict__ Biopack, const f16* __restrict__ Ufpack,
    const f16x2* __restrict__ accIn, f16x2* __restrict__ accOut,
    int poff, int ppoff, int mode, int zin)
{
  __shared__ f16 Ah[4][16*104];    // 4 x 3328 B  (rows 16, stride 104, cols 0..95 used)
  __shared__ f16 FAf[4][16*68];    // 4 x 2176 B
  int lane = threadIdx.x & 63;
  int w    = threadIdx.x >> 6;
  int j0   = (blockIdx.x*4 + w)*16;
  int q = lane>>4, c16 = lane&15;
  f16* AhW  = &Ah[w][0];
  f16* FAfW = &FAf[w][0];

  // ---- phase 1a: child emb -> Ah cols 64..95 (one f16x8 gather per lane)
  {
    int i  = lane>>2, cb = lane&3;
    int j  = j0 + i; if (j > PER-1) j = PER-1;
    int tk = tok[poff + j];
    f16x8 xv = *(const f16x8*)(emb16 + (size_t)tk*EDIM + cb*8);
    *(f16x8*)(AhW + i*104 + 64 + cb*8) = xv;
  }
  // ---- phase 1b: own accumulated child-sums (contiguous) -> LDS transpose
  if (mode != 0){
    #pragma unroll
    for (int i=0;i<16;i++){
      int j = j0 + i; if (j > PER-1) j = PER-1;
      f16x2 v = accIn[(size_t)j*HDIM + lane];
      AhW[i*104 + lane]  = v.x;
      FAfW[i*68 + lane] = v.y;
    }
  } else {
    #pragma unroll
    for (int i=0;i<16;i++)
      FAfW[i*68 + lane] = (f16)0.f;
  }
  f16x8 A2 = *(const f16x8*)(AhW + c16*104 + 64 + q*8);

  // zero own accIn rows for reuse as the atomic target at the next level.
  // (reads above already consumed; stores drain under the MFMA phase.
  //  clamped duplicate rows (j>=PER) are only read by lanes whose outputs
  //  are discarded, so the read/zero race there is benign.)
  if (mode != 0 && zin){
    f16x2 z; z.x = (f16)0.f; z.y = (f16)0.f;
    #pragma unroll
    for (int i=0;i<16;i++){
      int j = j0 + i;
      if (j < PER) ((f16x2*)accIn)[(size_t)j*HDIM + lane] = z;
    }
  }

  // ---- phase 2: iou MFMA (K=96) + epilogue
  const f16x8* Bp = (const f16x8*)Biopack;
  f32x4 acc[12];
  #pragma unroll
  for (int nt=0;nt<12;nt++) acc[nt] = (f32x4){0.f,0.f,0.f,0.f};
  #pragma unroll
  for (int nt=0;nt<12;nt++){
    f16x8 B2 = Bp[(24+nt)*64 + lane];
    acc[nt] = __builtin_amdgcn_mfma_f32_16x16x32_f16(A2, B2, acc[nt], 0,0,0);
  }
  if (mode != 0){
    f16x8 A0 = *(const f16x8*)(AhW + c16*104 + q*8);
    f16x8 A1 = *(const f16x8*)(AhW + c16*104 + 32 + q*8);
    #pragma unroll
    for (int nt=0;nt<12;nt++){
      f16x8 B0 = Bp[nt*64 + lane];
      f16x8 B1 = Bp[(12+nt)*64 + lane];
      acc[nt] = __builtin_amdgcn_mfma_f32_16x16x32_f16(A0, B0, acc[nt], 0,0,0);
      acc[nt] = __builtin_amdgcn_mfma_f32_16x16x32_f16(A1, B1, acc[nt], 0,0,0);
    }
  }
  float cc[4][4];
  f16   hh[4][4];
  int   prow_[4]; bool ok_[4];
  #pragma unroll
  for (int r=0;r<4;r++){
    int j = j0 + q*4 + r;
    bool ok = j < PER;
    int jl = ok ? j : PER-1;
    int g = poff + jl;
    ok_[r] = ok;
    prow_[r] = (mode != 2) ? (parent[g] - ppoff) : jl;
    int prow = q*4 + r;
    #pragma unroll
    for (int nt=0;nt<4;nt++){
      int col = nt*16 + c16;
      float ai = acc[nt][r]   + biou[col];
      float ao = acc[nt+4][r] + biou[64+col];
      float au = acc[nt+8][r] + biou[128+col];
      float fav = (float)FAfW[prow*68 + col];
      float c = sigf(ai)*tanh_f(au) + fav;
      float h = sigf(ao)*tanh_f(c);
      cc[r][nt] = c;
      hh[r][nt] = (f16)h;
    }
  }
  // ---- phase 3: h -> Ah cols 0..63, parent emb -> cols 64..95, Uf MFMA, push {h,fc}
  #pragma unroll
  for (int r=0;r<4;r++)
    #pragma unroll
    for (int nt=0;nt<4;nt++)
      AhW[(q*4+r)*104 + nt*16 + c16] = hh[r][nt];
  {
    int i  = lane>>2, cb = lane&3;
    int j  = j0 + i; if (j > PER-1) j = PER-1;
    int pg = (mode != 2) ? parent[poff + j] : 0;
    int ptk = tok[pg];
    f16x8 pv = *(const f16x8*)(emb16 + (size_t)ptk*EDIM + cb*8);
    *(f16x8*)(AhW + i*104 + 64 + cb*8) = pv;
  }
  f16x8 H0 = *(const f16x8*)(AhW + c16*104 + q*8);
  f16x8 H1 = *(const f16x8*)(AhW + c16*104 + 32 + q*8);
  f16x8 H2 = *(const f16x8*)(AhW + c16*104 + 64 + q*8);
  const f16x8* Up = (const f16x8*)Ufpack;
  f32x4 g4[4];
  #pragma unroll
  for (int nt=0;nt<4;nt++) g4[nt] = (f32x4){0.f,0.f,0.f,0.f};
  #pragma unroll
  for (int nt=0;nt<4;nt++){
    f16x8 B0 = Up[nt*64 + lane];
    f16x8 B1 = Up[(4+nt)*64 + lane];
    f16x8 B2 = Up[(8+nt)*64 + lane];
    g4[nt] = __builtin_amdgcn_mfma_f32_16x16x32_f16(H0, B0, g4[nt], 0,0,0);
    g4[nt] = __builtin_amdgcn_mfma_f32_16x16x32_f16(H1, B1, g4[nt], 0,0,0);
    g4[nt] = __builtin_amdgcn_mfma_f32_16x16x32_f16(H2, B2, g4[nt], 0,0,0);
  }
  #pragma unroll
  for (int r=0;r<4;r++){
    if (!ok_[r]) continue;
    size_t rb = (size_t)prow_[r]*HDIM;
    #pragma unroll
    for (int nt=0;nt<4;nt++){
      int col = nt*16 + c16;
      float v = sigf(g4[nt][r] + bf[col]) * cc[r][nt];
      if (mode == 2){
        f16x2 o; o.x = hh[r][nt]; o.y = (f16)v;
        accOut[rb + col] = o;
      } else {
        atomAddH2(&accOut[rb + col], hh[r][nt], (f16)v);
      }
    }
  }
}

// ================= root =================
__global__ __launch_bounds__(256) void rootred_kernel(
    const f16x2* __restrict__ HFin, float* __restrict__ rootacc)
{
  int t = blockIdx.x*blockDim.x + threadIdx.x;
  int m = t & 63;
  int j0 = t >> 6;
  int jstep = (gridDim.x*blockDim.x) >> 6;
  float af=0.f, ah=0.f;
  for (int j=j0; j<PER; j+=jstep){
    f16x2 v = HFin[(size_t)j*HDIM + m];
    ah += (float)v.x;
    af += (float)v.y;
  }
  __shared__ float red[256];
  red[threadIdx.x]=af; __syncthreads();
  if (threadIdx.x < 64) atomicAdd(&rootacc[m],    red[m]+red[64+m]+red[128+m]+red[192+m]);
  __syncthreads();
  red[threadIdx.x]=ah; __syncthreads();
  if (threadIdx.x < 64) atomicAdd(&rootacc[64+m], red[m]+red[64+m]+red[128+m]+red[192+m]);
}

__global__ void rootnode_kernel(
    const int* __restrict__ tok, const float* __restrict__ emb,
    const float* __restrict__ Wiou, const float* __restrict__ biou, const float* __restrict__ Uiou,
    const float* __restrict__ rootacc, float* __restrict__ out)
{
  int m = threadIdx.x;
  if (m >= HDIM) return;
  int t = tok[0];
  float ai=biou[m], ao=biou[HDIM+m], au=biou[2*HDIM+m];
  for (int e=0;e<EDIM;e++){
    float xe = emb[(size_t)t*EDIM+e];
    ai += Wiou[(size_t)m*EDIM+e]*xe;
    ao += Wiou[(size_t)(HDIM+m)*EDIM+e]*xe;
    au += Wiou[(size_t)(2*HDIM+m)*EDIM+e]*xe;
  }
  for (int k=0;k<HDIM;k++){
    float hv = rootacc[64+k];
    ai += Uiou[(size_t)m*HDIM+k]*hv;
    ao += Uiou[(size_t)(HDIM+m)*HDIM+k]*hv;
    au += Uiou[(size_t)(2*HDIM+m)*HDIM+k]*hv;
  }
  float c = sigf(ai)*tanh_f(au) + rootacc[m];
  out[m] = sigf(ao)*tanh_f(c);
}

// ================= launch =================
static inline char* alignup(char* p){
  uintptr_t u = (uintptr_t)p;
  u = (u + 255) & ~(uintptr_t)255;
  return (char*)u;
}

extern "C" void kernel_launch(void* const* d_in, const int* in_sizes, int n_in,
                              void* d_out, int out_size, void* d_ws, size_t ws_size,
                              hipStream_t stream)
{
  const int*   tok    = (const int*)d_in[0];
  const int*   parent = (const int*)d_in[1];
  const float* emb    = (const float*)d_in[4];
  const float* Wiou   = (const float*)d_in[5];
  const float* biou   = (const float*)d_in[6];
  const float* Uiou   = (const float*)d_in[7];
  const float* Wf     = (const float*)d_in[8];
  const float* bf     = (const float*)d_in[9];
  const float* Uf     = (const float*)d_in[10];
  float* out = (float*)d_out;

  char* w = (char*)d_ws;
  size_t BUF = (size_t)PER*HDIM*sizeof(f16x2);     // 38.3 MB
  f16x2* bufA    = (f16x2*)w;  w = alignup(w + BUF);
  f16x2* bufB    = (f16x2*)w;  w = alignup(w + BUF);
  float* rootacc = (float*)w;  w = alignup(w + 128*sizeof(float));
  f16*   emb16   = (f16*)w;    w = alignup(w + 1024*EDIM*sizeof(f16));
  f16*   Ufpack  = (f16*)w;    w = alignup(w + 3*4*64*8*sizeof(f16));
  f16*   Biopack = (f16*)w;    w = alignup(w + 3*12*64*8*sizeof(f16));

  const int NB = (PER + 63)/64;   // 2341 blocks of 256 threads (4 waves x 16 nodes)

  (void)hipMemsetAsync(rootacc, 0, 128*sizeof(float), stream);
  (void)hipMemsetAsync(bufA, 0, BUF, stream);
  (void)hipMemsetAsync(bufB, 0, BUF, stream);
  tablepack_kernel<<<1025, 256, 0, stream>>>(emb, Wiou, Wf, Uf, Uiou,
                                             emb16, Ufpack, Biopack);

  // level d kernel: nodes at poff=1+(d-1)*PER; parents at ppoff=1+(d-2)*PER
  // d=7 (leaves): mode 0 -> atomic into bufA (accum for level 6)
  // d=6..2:       mode 1 -> read own accum, atomic into other buf
  //               zin=1 for d>=3: zero accIn in-kernel (it is the atomic
  //               target at the next level) instead of a memset dispatch.
  // d=1:          mode 2 -> read own accum, plain write {h,fc} (for rootred)
  f16x2* accIn  = nullptr;
  f16x2* accOut = bufA;
  level_kernel<<<NB, 256, 0, stream>>>(tok, parent, emb16, biou, bf, Biopack, Ufpack,
                                       nullptr, bufA, 1 + 6*PER, 1 + 5*PER, 0, 0);
  accIn = bufA; accOut = bufB;
  for (int d=6; d>=2; --d){
    level_kernel<<<NB, 256, 0, stream>>>(tok, parent, emb16, biou, bf, Biopack, Ufpack,
                                         accIn, accOut, 1 + (d-1)*PER, 1 + (d-2)*PER, 1,
                                         (d >= 3) ? 1 : 0);
    f16x2* t2 = accIn; accIn = accOut; accOut = t2;
  }
  // d=1: plain contiguous write into accOut (full overwrite, no zero needed)
  level_kernel<<<NB, 256, 0, stream>>>(tok, parent, emb16, biou, bf, Biopack, Ufpack,
                                       accIn, accOut, 1, 0, 2, 0);

  rootred_kernel<<<256, 256, 0, stream>>>(accOut, rootacc);
  rootnode_kernel<<<1, 64, 0, stream>>>(tok, emb, Wiou, biou, Uiou, rootacc, out);
}